// Round 1
// baseline (335.785 us; speedup 1.0000x reference)
//
#include <hip/hip_runtime.h>
#include <math.h>

#define DD 160
#define HH 160
#define WW 160
#define NB 2   // B*C

static constexpr float EPS = 1e-12f;
// out = -(sum of six cosine sums) / (160*2*3)
static constexpr float SCALE = -1.0f / 960.0f;

__global__ void zero_kernel(float* out) {
  if (threadIdx.x == 0) out[0] = 0.0f;
}

// cos along W for gx (diff along D) and gy (diff along H).
// One block per (b,d) slice; 8 groups of 32 lanes, each group reduces one row.
__global__ __launch_bounds__(256) void rows_kernel(const float* __restrict__ f,
                                                   const float* __restrict__ t,
                                                   float* __restrict__ out) {
  const int bd = blockIdx.x;           // b*DD + d
  const int d = bd % DD;
  const int tid = threadIdx.x;
  const int g = tid >> 5;              // row group 0..7
  const int l = tid & 31;              // lane in group
  __shared__ __align__(16) float fA[9 * WW];
  __shared__ __align__(16) float tA[9 * WW];
  __shared__ __align__(16) float fB[8 * WW];
  __shared__ __align__(16) float tB[8 * WW];
  __shared__ float part[8];

  const size_t base = (size_t)bd * HH * WW;
  const float* fp = f + base;
  const float* tp = t + base;
  const bool has_d1 = (d < DD - 1);
  float acc = 0.0f;

  for (int h0 = 0; h0 < HH; h0 += 8) {
    const int nA = (h0 + 8 < HH) ? 9 : 8;   // include row h0+8 for gy unless OOB
    __syncthreads();
    {
      const float4* s4f = reinterpret_cast<const float4*>(fp + h0 * WW);
      const float4* s4t = reinterpret_cast<const float4*>(tp + h0 * WW);
      float4* d4f = reinterpret_cast<float4*>(fA);
      float4* d4t = reinterpret_cast<float4*>(tA);
      for (int i = tid; i < nA * (WW / 4); i += 256) { d4f[i] = s4f[i]; d4t[i] = s4t[i]; }
      if (has_d1) {
        const float4* s4fb = reinterpret_cast<const float4*>(fp + HH * WW + h0 * WW);
        const float4* s4tb = reinterpret_cast<const float4*>(tp + HH * WW + h0 * WW);
        float4* d4fb = reinterpret_cast<float4*>(fB);
        float4* d4tb = reinterpret_cast<float4*>(tB);
        for (int i = tid; i < 8 * (WW / 4); i += 256) { d4fb[i] = s4fb[i]; d4tb[i] = s4tb[i]; }
      }
    }
    __syncthreads();

    const int h = h0 + g;
    const bool has_h1 = (h < HH - 1);
    float xd = 0, xf = 0, xt = 0, yd = 0, yf = 0, yt = 0;
#pragma unroll
    for (int k = 0; k < 5; ++k) {
      const int w = l + 32 * k;
      const float f0 = fA[g * WW + w];
      const float t0 = tA[g * WW + w];
      float gxf = 0, gxt = 0, gyf = 0, gyt = 0;
      if (has_d1) { gxf = fB[g * WW + w] - f0; gxt = tB[g * WW + w] - t0; }
      if (has_h1) { gyf = fA[(g + 1) * WW + w] - f0; gyt = tA[(g + 1) * WW + w] - t0; }
      xd += gxf * gxt; xf += gxf * gxf; xt += gxt * gxt;
      yd += gyf * gyt; yf += gyf * gyf; yt += gyt * gyt;
    }
    // reduce 6 sums across the 32-lane group (xor masks stay inside the group)
#pragma unroll
    for (int m = 16; m >= 1; m >>= 1) {
      xd += __shfl_xor(xd, m); xf += __shfl_xor(xf, m); xt += __shfl_xor(xt, m);
      yd += __shfl_xor(yd, m); yf += __shfl_xor(yf, m); yt += __shfl_xor(yt, m);
    }
    if (l == 0) {
      acc += xd / (fmaxf(sqrtf(xf), EPS) * fmaxf(sqrtf(xt), EPS));
      acc += yd / (fmaxf(sqrtf(yf), EPS) * fmaxf(sqrtf(yt), EPS));
    }
  }

  if (l == 0) part[g] = acc;
  __syncthreads();
  if (tid == 0) {
    float s = 0;
#pragma unroll
    for (int i = 0; i < 8; ++i) s += part[i];
    atomicAdd(out, s * SCALE);
  }
}

// cos along H for gx (diff along D) and gz (diff along W).
// One block per (b,d); thread w accumulates its column over h.
__global__ __launch_bounds__(192) void colsH_kernel(const float* __restrict__ f,
                                                    const float* __restrict__ t,
                                                    float* __restrict__ out) {
  const int bd = blockIdx.x;           // b*DD + d
  const int d = bd % DD;
  const int tid = threadIdx.x;
  const int w = tid;
  const size_t base = (size_t)bd * HH * WW;
  const float* fp = f + base;
  const float* tp = t + base;
  const bool active = (w < WW);
  const bool has_d1 = (d < DD - 1);
  const bool has_w1 = (w < WW - 1);
  float xd = 0, xf = 0, xt = 0, zd = 0, zf = 0, zt = 0;
  if (active) {
#pragma unroll 4
    for (int h = 0; h < HH; ++h) {
      const int o = h * WW + w;
      const float f0 = fp[o], t0 = tp[o];
      float gxf = 0, gxt = 0, gzf = 0, gzt = 0;
      if (has_d1) { gxf = fp[o + HH * WW] - f0; gxt = tp[o + HH * WW] - t0; }
      if (has_w1) { gzf = fp[o + 1] - f0; gzt = tp[o + 1] - t0; }
      xd += gxf * gxt; xf += gxf * gxf; xt += gxt * gxt;
      zd += gzf * gzt; zf += gzf * gzf; zt += gzt * gzt;
    }
  }
  float v = 0;
  if (active) {
    v = xd / (fmaxf(sqrtf(xf), EPS) * fmaxf(sqrtf(xt), EPS))
      + zd / (fmaxf(sqrtf(zf), EPS) * fmaxf(sqrtf(zt), EPS));
  }
  __shared__ float red[192];
  red[tid] = v;
  __syncthreads();
  if (tid == 0) {
    float s = 0;
    for (int i = 0; i < 192; ++i) s += red[i];
    atomicAdd(out, s * SCALE);
  }
}

// cos along D for gy (diff along H) and gz (diff along W).
// One block per (b,h); thread w accumulates its column over d.
__global__ __launch_bounds__(192) void colsD_kernel(const float* __restrict__ f,
                                                    const float* __restrict__ t,
                                                    float* __restrict__ out) {
  const int bh = blockIdx.x;           // b*HH + h
  const int b = bh / HH;
  const int h = bh % HH;
  const int tid = threadIdx.x;
  const int w = tid;
  const float* fp = f + (size_t)b * DD * HH * WW + (size_t)h * WW;
  const float* tp = t + (size_t)b * DD * HH * WW + (size_t)h * WW;
  const bool active = (w < WW);
  const bool has_h1 = (h < HH - 1);
  const bool has_w1 = (w < WW - 1);
  float yd = 0, yf = 0, yt = 0, zd = 0, zf = 0, zt = 0;
  if (active) {
#pragma unroll 4
    for (int d = 0; d < DD; ++d) {
      const size_t o = (size_t)d * HH * WW + w;
      const float f0 = fp[o], t0 = tp[o];
      float gyf = 0, gyt = 0, gzf = 0, gzt = 0;
      if (has_h1) { gyf = fp[o + WW] - f0; gyt = tp[o + WW] - t0; }
      if (has_w1) { gzf = fp[o + 1] - f0; gzt = tp[o + 1] - t0; }
      yd += gyf * gyt; yf += gyf * gyf; yt += gyt * gyt;
      zd += gzf * gzt; zf += gzf * gzf; zt += gzt * gzt;
    }
  }
  float v = 0;
  if (active) {
    v = yd / (fmaxf(sqrtf(yf), EPS) * fmaxf(sqrtf(yt), EPS))
      + zd / (fmaxf(sqrtf(zf), EPS) * fmaxf(sqrtf(zt), EPS));
  }
  __shared__ float red[192];
  red[tid] = v;
  __syncthreads();
  if (tid == 0) {
    float s = 0;
    for (int i = 0; i < 192; ++i) s += red[i];
    atomicAdd(out, s * SCALE);
  }
}

extern "C" void kernel_launch(void* const* d_in, const int* in_sizes, int n_in,
                              void* d_out, int out_size, void* d_ws, size_t ws_size,
                              hipStream_t stream) {
  const float* fk = (const float*)d_in[0];
  const float* tr = (const float*)d_in[1];
  float* out = (float*)d_out;
  hipLaunchKernelGGL(zero_kernel, dim3(1), dim3(64), 0, stream, out);
  hipLaunchKernelGGL(rows_kernel,  dim3(NB * DD), dim3(256), 0, stream, fk, tr, out);
  hipLaunchKernelGGL(colsH_kernel, dim3(NB * DD), dim3(192), 0, stream, fk, tr, out);
  hipLaunchKernelGGL(colsD_kernel, dim3(NB * HH), dim3(192), 0, stream, fk, tr, out);
}

// Round 2
// 192.388 us; speedup vs baseline: 1.7454x; 1.7454x over previous
//
#include <hip/hip_runtime.h>
#include <math.h>

#define DD 160
#define HH 160
#define WW 160
#define NB 2                 // B*C
#define SLICE (HH * WW)      // 25600
#define NV 51200             // vectors per reduction type = NB*160*160
#define NVTOT (4 * NV)       // gxH, gzH, gyD, gzD

static constexpr float EPS = 1e-12f;
static constexpr float SCALE = -1.0f / 960.0f;  // -(sum of six cos sums)/(160*2*3)

__global__ void zero_kernel(float* out) {
  if (threadIdx.x == 0) out[0] = 0.0f;
}

// ---------------------------------------------------------------------------
// gx,gy cosines along W. One block per (b, d, h-chunk of 16).
// 8 groups of 32 lanes; each group fully reduces 2 rows.
// ---------------------------------------------------------------------------
__global__ __launch_bounds__(256) void rows_kernel(const float* __restrict__ f,
                                                   const float* __restrict__ t,
                                                   float* __restrict__ out) {
  const int blk = blockIdx.x;          // bd*10 + hc
  const int hc = blk % 10;
  const int bd = blk / 10;
  const int d = bd % DD;
  const int tid = threadIdx.x;
  const int g = tid >> 5;
  const int l = tid & 31;
  const size_t base = (size_t)bd * SLICE;
  const int doff = (d < DD - 1) ? SLICE : 0;   // clamped d+1 -> gradient 0
  float acc = 0.0f;

#pragma unroll
  for (int r = 0; r < 2; ++r) {
    const int h = hc * 16 + g * 2 + r;
    const int hoff = (h < HH - 1) ? WW : 0;    // clamped h+1 -> gradient 0
    const float* fp = f + base + (size_t)h * WW;
    const float* tp = t + base + (size_t)h * WW;
    float xd = 0, xf = 0, xt = 0, yd = 0, yf = 0, yt = 0;
#pragma unroll
    for (int k = 0; k < 5; ++k) {
      const int w = l + 32 * k;
      const float f0 = fp[w], t0 = tp[w];
      const float gxf = fp[doff + w] - f0, gxt = tp[doff + w] - t0;
      const float gyf = fp[hoff + w] - f0, gyt = tp[hoff + w] - t0;
      xd += gxf * gxt; xf += gxf * gxf; xt += gxt * gxt;
      yd += gyf * gyt; yf += gyf * gyf; yt += gyt * gyt;
    }
#pragma unroll
    for (int m = 16; m >= 1; m >>= 1) {
      xd += __shfl_xor(xd, m); xf += __shfl_xor(xf, m); xt += __shfl_xor(xt, m);
      yd += __shfl_xor(yd, m); yf += __shfl_xor(yf, m); yt += __shfl_xor(yt, m);
    }
    if (l == 0) {
      acc += xd / (fmaxf(sqrtf(xf), EPS) * fmaxf(sqrtf(xt), EPS));
      acc += yd / (fmaxf(sqrtf(yf), EPS) * fmaxf(sqrtf(yt), EPS));
    }
  }

  __shared__ float part[8];
  if (l == 0) part[g] = acc;
  __syncthreads();
  if (tid == 0) {
    float s = 0;
#pragma unroll
    for (int i = 0; i < 8; ++i) s += part[i];
    atomicAdd(out, s * SCALE);
  }
}

// ---------------------------------------------------------------------------
// gx,gz partials along H. One block per (b, d, h-chunk of 80).
// 640 threads: (w = tid%160, hs = tid/160); thread sums 20 rows.
// Writes 3-float partials per (vector, chunk) to P.
// ---------------------------------------------------------------------------
__global__ __launch_bounds__(640) void colsH_kernel(const float* __restrict__ f,
                                                    const float* __restrict__ t,
                                                    float* __restrict__ P) {
  const int blk = blockIdx.x;          // bd*2 + hc
  const int hc = blk & 1;
  const int bd = blk >> 1;
  const int d = bd % DD;
  const int tid = threadIdx.x;
  const int w = tid % 160;
  const int hs = tid / 160;
  const size_t base = (size_t)bd * SLICE;
  const int doff = (d < DD - 1) ? SLICE : 0;
  const int w1 = (w < WW - 1) ? 1 : 0;

  float xd = 0, xf = 0, xt = 0, zd = 0, zf = 0, zt = 0;
#pragma unroll 4
  for (int j = 0; j < 20; ++j) {
    const int h = hc * 80 + hs + 4 * j;
    const float* fp = f + base + (size_t)h * WW;
    const float* tp = t + base + (size_t)h * WW;
    const float f0 = fp[w], t0 = tp[w];
    const float gxf = fp[doff + w] - f0, gxt = tp[doff + w] - t0;
    const float gzf = fp[w + w1] - f0, gzt = tp[w + w1] - t0;
    xd += gxf * gxt; xf += gxf * gxf; xt += gxt * gxt;
    zd += gzf * gzt; zf += gzf * gzf; zt += gzt * gzt;
  }

  __shared__ float sd[4][160][7];      // stride 7 -> conflict-free
  sd[hs][w][0] = xd; sd[hs][w][1] = xf; sd[hs][w][2] = xt;
  sd[hs][w][3] = zd; sd[hs][w][4] = zf; sd[hs][w][5] = zt;
  __syncthreads();
  if (tid < 160) {
    float a[6];
#pragma unroll
    for (int j = 0; j < 6; ++j)
      a[j] = sd[0][tid][j] + sd[1][tid][j] + sd[2][tid][j] + sd[3][tid][j];
    const int vx = bd * 160 + tid;           // gx-alongH
    const int vz = NV + bd * 160 + tid;      // gz-alongH
    P[(size_t)vx * 6 + hc * 3 + 0] = a[0];
    P[(size_t)vx * 6 + hc * 3 + 1] = a[1];
    P[(size_t)vx * 6 + hc * 3 + 2] = a[2];
    P[(size_t)vz * 6 + hc * 3 + 0] = a[3];
    P[(size_t)vz * 6 + hc * 3 + 1] = a[4];
    P[(size_t)vz * 6 + hc * 3 + 2] = a[5];
  }
}

// ---------------------------------------------------------------------------
// gy,gz partials along D. One block per (b, h, d-chunk of 80).
// 640 threads: (w = tid%160, ds = tid/160); thread sums 20 slices.
// ---------------------------------------------------------------------------
__global__ __launch_bounds__(640) void colsD_kernel(const float* __restrict__ f,
                                                    const float* __restrict__ t,
                                                    float* __restrict__ P) {
  const int blk = blockIdx.x;          // bh*2 + dc
  const int dc = blk & 1;
  const int bh = blk >> 1;
  const int b = bh / HH;
  const int h = bh % HH;
  const int tid = threadIdx.x;
  const int w = tid % 160;
  const int ds = tid / 160;
  const size_t base = (size_t)b * DD * SLICE + (size_t)h * WW;
  const int hoff = (h < HH - 1) ? WW : 0;
  const int w1 = (w < WW - 1) ? 1 : 0;

  float yd = 0, yf = 0, yt = 0, zd = 0, zf = 0, zt = 0;
#pragma unroll 4
  for (int j = 0; j < 20; ++j) {
    const int d = dc * 80 + ds + 4 * j;
    const float* fp = f + base + (size_t)d * SLICE;
    const float* tp = t + base + (size_t)d * SLICE;
    const float f0 = fp[w], t0 = tp[w];
    const float gyf = fp[hoff + w] - f0, gyt = tp[hoff + w] - t0;
    const float gzf = fp[w + w1] - f0, gzt = tp[w + w1] - t0;
    yd += gyf * gyt; yf += gyf * gyf; yt += gyt * gyt;
    zd += gzf * gzt; zf += gzf * gzf; zt += gzt * gzt;
  }

  __shared__ float sd[4][160][7];
  sd[ds][w][0] = yd; sd[ds][w][1] = yf; sd[ds][w][2] = yt;
  sd[ds][w][3] = zd; sd[ds][w][4] = zf; sd[ds][w][5] = zt;
  __syncthreads();
  if (tid < 160) {
    float a[6];
#pragma unroll
    for (int j = 0; j < 6; ++j)
      a[j] = sd[0][tid][j] + sd[1][tid][j] + sd[2][tid][j] + sd[3][tid][j];
    const int vy = 2 * NV + bh * 160 + tid;  // gy-alongD
    const int vz = 3 * NV + bh * 160 + tid;  // gz-alongD
    P[(size_t)vy * 6 + dc * 3 + 0] = a[0];
    P[(size_t)vy * 6 + dc * 3 + 1] = a[1];
    P[(size_t)vy * 6 + dc * 3 + 2] = a[2];
    P[(size_t)vz * 6 + dc * 3 + 0] = a[3];
    P[(size_t)vz * 6 + dc * 3 + 1] = a[4];
    P[(size_t)vz * 6 + dc * 3 + 2] = a[5];
  }
}

// ---------------------------------------------------------------------------
// Combine chunk partials -> cosines -> loss.
// ---------------------------------------------------------------------------
__global__ __launch_bounds__(256) void finalize_kernel(const float* __restrict__ P,
                                                       float* __restrict__ out) {
  const int v = blockIdx.x * 256 + threadIdx.x;
  float c = 0.0f;
  if (v < NVTOT) {
    const float dot = P[(size_t)v * 6 + 0] + P[(size_t)v * 6 + 3];
    const float ff  = P[(size_t)v * 6 + 1] + P[(size_t)v * 6 + 4];
    const float tt  = P[(size_t)v * 6 + 2] + P[(size_t)v * 6 + 5];
    c = dot / (fmaxf(sqrtf(ff), EPS) * fmaxf(sqrtf(tt), EPS));
  }
#pragma unroll
  for (int m = 32; m >= 1; m >>= 1) c += __shfl_xor(c, m);
  __shared__ float part[4];
  const int wv = threadIdx.x >> 6;
  if ((threadIdx.x & 63) == 0) part[wv] = c;
  __syncthreads();
  if (threadIdx.x == 0) {
    const float s = part[0] + part[1] + part[2] + part[3];
    atomicAdd(out, s * SCALE);
  }
}

extern "C" void kernel_launch(void* const* d_in, const int* in_sizes, int n_in,
                              void* d_out, int out_size, void* d_ws, size_t ws_size,
                              hipStream_t stream) {
  const float* fk = (const float*)d_in[0];
  const float* tr = (const float*)d_in[1];
  float* out = (float*)d_out;
  float* P = (float*)d_ws;             // NVTOT*6 floats = 4.9 MB

  hipLaunchKernelGGL(zero_kernel, dim3(1), dim3(64), 0, stream, out);
  hipLaunchKernelGGL(rows_kernel,  dim3(NB * DD * 10), dim3(256), 0, stream, fk, tr, out);
  hipLaunchKernelGGL(colsH_kernel, dim3(NB * DD * 2),  dim3(640), 0, stream, fk, tr, P);
  hipLaunchKernelGGL(colsD_kernel, dim3(NB * HH * 2),  dim3(640), 0, stream, fk, tr, P);
  hipLaunchKernelGGL(finalize_kernel, dim3((NVTOT + 255) / 256), dim3(256), 0, stream, P, out);
}

// Round 3
// 149.553 us; speedup vs baseline: 2.2453x; 1.2864x over previous
//
#include <hip/hip_runtime.h>
#include <math.h>

#define DD 160
#define HH 160
#define WW 160
#define NB 2
#define SLICE (HH * WW)        // 25600
#define NV 51200               // NB*160*160 vectors per reduction type
#define NVTOT (4 * NV)         // gxH, gzH, gyD, gzD
#define W4 40                  // float4 chunks per row
#define NTHR 320               // 8 row-groups x 40 lanes

static constexpr float EPS = 1e-12f;
static constexpr float SCALE = -1.0f / 960.0f;  // -(six cos sums)/(160*2*3)

#define ELEM(v, j) ((j) == 0 ? (v).x : ((j) == 1 ? (v).y : ((j) == 2 ? (v).z : (v).w)))

__global__ void zero_kernel(float* out) {
  if (threadIdx.x == 0) out[0] = 0.0f;
}

// ---------------------------------------------------------------------------
// Kernel A (h-major): alongW cosines (gx,gy) + alongH partials (gx,gz).
// Block = (b*DD+d, h-chunk). 8 groups x 40 float4-lanes; group g handles rows
// it*8+g within the chunk. Clamped neighbor loads make boundary grads 0.
// ---------------------------------------------------------------------------
__global__ __launch_bounds__(NTHR) void kernelA(const float* __restrict__ f,
                                                const float* __restrict__ t,
                                                float* __restrict__ P,
                                                float* __restrict__ out,
                                                int nc, int rows_pc, int niter) {
  const int tid = threadIdx.x;
  const int l = tid % W4;
  const int g = tid / W4;
  const int w = 4 * l;
  const int hc = blockIdx.x % nc;
  const int bd = blockIdx.x / nc;
  const int d = bd % DD;
  const size_t base = (size_t)bd * SLICE;
  const float* fp = f + base;
  const float* tp = t + base;
  const int dstep = (d < DD - 1) ? SLICE : 0;          // clamp -> gx = 0
  const int wn = (w + 4 < WW) ? (w + 4) : (WW - 1);    // clamp -> gz[3] = 0 at w=159

  __shared__ float sd[8][W4][25];
  __shared__ float red[8][6];
  __shared__ float cpart[8];

  float ah[24];
#pragma unroll
  for (int c = 0; c < 24; ++c) ah[c] = 0.0f;
  float accCos = 0.0f;

  for (int it = 0; it < niter; ++it) {
    const int h = hc * rows_pc + it * 8 + g;
    const float* rf = fp + h * WW;
    const float* rt = tp + h * WW;
    const int hstep = (h < HH - 1) ? WW : 0;           // clamp -> gy = 0
    const float4 F0 = *(const float4*)(rf + w);
    const float4 T0 = *(const float4*)(rt + w);
    const float4 FD = *(const float4*)(rf + dstep + w);
    const float4 TD = *(const float4*)(rt + dstep + w);
    const float4 FH = *(const float4*)(rf + hstep + w);
    const float4 TH = *(const float4*)(rt + hstep + w);
    const float fz = rf[wn], tz = rt[wn];

    float xd = 0, xf = 0, xt = 0, yd = 0, yf = 0, yt = 0;
#pragma unroll
    for (int j = 0; j < 4; ++j) {
      const float f0 = ELEM(F0, j), t0 = ELEM(T0, j);
      const float gxf = ELEM(FD, j) - f0, gxt = ELEM(TD, j) - t0;
      const float gyf = ELEM(FH, j) - f0, gyt = ELEM(TH, j) - t0;
      const float fnx = (j < 3) ? ELEM(F0, (j + 1)) : fz;
      const float tnx = (j < 3) ? ELEM(T0, (j + 1)) : tz;
      const float gzf = fnx - f0, gzt = tnx - t0;
      xd += gxf * gxt; xf += gxf * gxf; xt += gxt * gxt;
      yd += gyf * gyt; yf += gyf * gyf; yt += gyt * gyt;
      ah[j * 6 + 0] += gxf * gxt; ah[j * 6 + 1] += gxf * gxf; ah[j * 6 + 2] += gxt * gxt;
      ah[j * 6 + 3] += gzf * gzt; ah[j * 6 + 4] += gzf * gzf; ah[j * 6 + 5] += gzt * gzt;
    }
    // row (alongW) reduction over 40 lanes via LDS
    sd[g][l][0] = xd; sd[g][l][1] = xf; sd[g][l][2] = xt;
    sd[g][l][3] = yd; sd[g][l][4] = yf; sd[g][l][5] = yt;
    __syncthreads();
    if (tid < 48) {
      const int rr = tid / 6, c = tid % 6;
      float s = 0.0f;
#pragma unroll 8
      for (int ll = 0; ll < W4; ++ll) s += sd[rr][ll][c];
      red[rr][c] = s;
    }
    __syncthreads();
    if (tid < 8) {
      const float cx = red[tid][0] / (fmaxf(sqrtf(red[tid][1]), EPS) * fmaxf(sqrtf(red[tid][2]), EPS));
      const float cy = red[tid][3] / (fmaxf(sqrtf(red[tid][4]), EPS) * fmaxf(sqrtf(red[tid][5]), EPS));
      accCos += cx + cy;
    }
    __syncthreads();
  }

  if (tid < 8) cpart[tid] = accCos;
  // alongH: cross-group reduce of ah (reuse sd)
#pragma unroll
  for (int c = 0; c < 24; ++c) sd[g][l][c] = ah[c];
  __syncthreads();
  if (tid == 0) {
    float s = 0.0f;
#pragma unroll
    for (int i = 0; i < 8; ++i) s += cpart[i];
    atomicAdd(out, s * SCALE);
  }
  for (int task = tid; task < 960; task += NTHR) {
    const int ll = task / 24, c = task % 24;
    float s = 0.0f;
#pragma unroll
    for (int gg = 0; gg < 8; ++gg) s += sd[gg][ll][c];
    const int j = c / 6, cc = c % 6;
    const int wi = 4 * ll + j;
    const size_t vec = (cc < 3) ? (size_t)(bd * 160 + wi) : (size_t)(NV + bd * 160 + wi);
    P[((size_t)hc * NVTOT + vec) * 3 + (cc % 3)] = s;
  }
}

// ---------------------------------------------------------------------------
// Kernel B (d-major): alongD partials (gy,gz).
// Block = (b*HH+h, d-chunk). Group g handles slices it*8+g within the chunk.
// ---------------------------------------------------------------------------
__global__ __launch_bounds__(NTHR) void kernelB(const float* __restrict__ f,
                                                const float* __restrict__ t,
                                                float* __restrict__ P,
                                                int nc, int rows_pc, int niter) {
  const int tid = threadIdx.x;
  const int l = tid % W4;
  const int g = tid / W4;
  const int w = 4 * l;
  const int dc = blockIdx.x % nc;
  const int bh = blockIdx.x / nc;
  const int b = bh / HH;
  const int h = bh % HH;
  const size_t base = (size_t)b * DD * SLICE + (size_t)h * WW;
  const float* fp = f + base;
  const float* tp = t + base;
  const int hstep = (h < HH - 1) ? WW : 0;
  const int wn = (w + 4 < WW) ? (w + 4) : (WW - 1);

  __shared__ float sd[8][W4][25];
  float ad[24];
#pragma unroll
  for (int c = 0; c < 24; ++c) ad[c] = 0.0f;

  for (int it = 0; it < niter; ++it) {
    const int dloc = dc * rows_pc + it * 8 + g;
    const float* rf = fp + (size_t)dloc * SLICE;
    const float* rt = tp + (size_t)dloc * SLICE;
    const float4 F0 = *(const float4*)(rf + w);
    const float4 T0 = *(const float4*)(rt + w);
    const float4 FH = *(const float4*)(rf + hstep + w);
    const float4 TH = *(const float4*)(rt + hstep + w);
    const float fz = rf[wn], tz = rt[wn];
#pragma unroll
    for (int j = 0; j < 4; ++j) {
      const float f0 = ELEM(F0, j), t0 = ELEM(T0, j);
      const float gyf = ELEM(FH, j) - f0, gyt = ELEM(TH, j) - t0;
      const float fnx = (j < 3) ? ELEM(F0, (j + 1)) : fz;
      const float tnx = (j < 3) ? ELEM(T0, (j + 1)) : tz;
      const float gzf = fnx - f0, gzt = tnx - t0;
      ad[j * 6 + 0] += gyf * gyt; ad[j * 6 + 1] += gyf * gyf; ad[j * 6 + 2] += gyt * gyt;
      ad[j * 6 + 3] += gzf * gzt; ad[j * 6 + 4] += gzf * gzf; ad[j * 6 + 5] += gzt * gzt;
    }
  }
#pragma unroll
  for (int c = 0; c < 24; ++c) sd[g][l][c] = ad[c];
  __syncthreads();
  for (int task = tid; task < 960; task += NTHR) {
    const int ll = task / 24, c = task % 24;
    float s = 0.0f;
#pragma unroll
    for (int gg = 0; gg < 8; ++gg) s += sd[gg][ll][c];
    const int j = c / 6, cc = c % 6;
    const int wi = 4 * ll + j;
    const size_t vec = (cc < 3) ? (size_t)(2 * NV + bh * 160 + wi) : (size_t)(3 * NV + bh * 160 + wi);
    P[((size_t)dc * NVTOT + vec) * 3 + (cc % 3)] = s;
  }
}

// ---------------------------------------------------------------------------
// Combine chunk partials -> cosines -> loss.
// ---------------------------------------------------------------------------
__global__ __launch_bounds__(256) void finalize_kernel(const float* __restrict__ P,
                                                       float* __restrict__ out, int nc) {
  const int v = blockIdx.x * 256 + threadIdx.x;
  float c = 0.0f;
  if (v < NVTOT) {
    float dot = 0.0f, ff = 0.0f, tt = 0.0f;
    for (int ch = 0; ch < nc; ++ch) {
      const size_t o = ((size_t)ch * NVTOT + v) * 3;
      dot += P[o]; ff += P[o + 1]; tt += P[o + 2];
    }
    c = dot / (fmaxf(sqrtf(ff), EPS) * fmaxf(sqrtf(tt), EPS));
  }
#pragma unroll
  for (int m = 32; m >= 1; m >>= 1) c += __shfl_xor(c, m);
  __shared__ float part[4];
  if ((threadIdx.x & 63) == 0) part[threadIdx.x >> 6] = c;
  __syncthreads();
  if (threadIdx.x == 0) atomicAdd(out, (part[0] + part[1] + part[2] + part[3]) * SCALE);
}

extern "C" void kernel_launch(void* const* d_in, const int* in_sizes, int n_in,
                              void* d_out, int out_size, void* d_ws, size_t ws_size,
                              hipStream_t stream) {
  const float* fk = (const float*)d_in[0];
  const float* tr = (const float*)d_in[1];
  float* out = (float*)d_out;
  float* P = (float*)d_ws;

  const size_t need5 = (size_t)5 * NVTOT * 3 * sizeof(float);  // 12.3 MB
  const int nc = (ws_size >= need5) ? 5 : 2;                   // nc=2 path proven at 4.9 MB
  const int rows_pc = 160 / nc;
  const int niter = rows_pc / 8;

  hipLaunchKernelGGL(zero_kernel, dim3(1), dim3(64), 0, stream, out);
  hipLaunchKernelGGL(kernelA, dim3(NB * DD * nc), dim3(NTHR), 0, stream, fk, tr, P, out, nc, rows_pc, niter);
  hipLaunchKernelGGL(kernelB, dim3(NB * HH * nc), dim3(NTHR), 0, stream, fk, tr, P, nc, rows_pc, niter);
  hipLaunchKernelGGL(finalize_kernel, dim3((NVTOT + 255) / 256), dim3(256), 0, stream, P, out, nc);
}